// Round 1
// 140.702 us; speedup vs baseline: 1.0702x; 1.0702x over previous
//
#include <hip/hip_runtime.h>
#include <math.h>

#define T_ 30
#define C_ 512
#define N_ 784      // 28*28 = 49 tiles of 16
#define NA_ 800     // aT row pitch (25 ksteps of 32)
#define XPITCH 520  // LDS stage row pitch in ushorts (16B-aligned rows, 2-way-max banks)
#define EPSV 1e-12f

typedef __attribute__((ext_vector_type(8))) short bf16x8;
typedef __attribute__((ext_vector_type(4))) float f32x4;

__device__ __forceinline__ unsigned short f2bf(float f) {
    union { float f; unsigned int u; } v; v.f = f;
    unsigned int r = (v.u + 0x7FFFu + ((v.u >> 16) & 1u)) >> 16;  // RNE
    return (unsigned short)r;
}
__device__ __forceinline__ float bf2f(unsigned short h) {
    union { unsigned int u; float f; } v; v.u = ((unsigned int)h) << 16;
    return v.f;
}

// wh/wl: split-precision bf16 of w, layout [k][c]
__global__ void k_prep(const float* __restrict__ w, unsigned short* __restrict__ wh,
                       unsigned short* __restrict__ wl) {
    int idx = blockIdx.x * 256 + threadIdx.x;  // 0..32767
    float v = w[idx];
    unsigned short h = f2bf(v);
    wh[idx] = h;
    wl[idx] = f2bf(v - bf2f(h));
}

// Fused invnorm + logits (3-product split-bf16 MFMA) + softmax + aT + asum.
// grid (49, 30), 256 thr. Block: 16 n x 64 k, c-reduction split over 4 waves.
// v2: wave-private staging (one barrier less), register-double-buffered w
// fragments, batched x loads, interleaved softmax rows, fused aT tail-zero.
__global__ __launch_bounds__(256, 4) void k_assign(
    const float* __restrict__ x, const unsigned short* __restrict__ wh,
    const unsigned short* __restrict__ wl, const float* __restrict__ b,
    unsigned short* __restrict__ aT, float* __restrict__ asum)
{
    // stage: xh/xl [16 n][XPITCH c]; red (union, reused after MFMA): [4 w][16 n][68 k]
    __shared__ __align__(16) char smem[2 * 16 * XPITCH * 2];  // 33280 B >= red 17408 B
    unsigned short* xh = (unsigned short*)smem;
    unsigned short* xl = xh + 16 * XPITCH;
    float* red = (float*)smem;
    __shared__ float ssq[4][16];

    int t = blockIdx.y, n0 = blockIdx.x * 16;
    int tid = threadIdx.x;
    int w = tid >> 6, L = tid & 63, lid = L & 15, quad = L >> 4;
    int cbase = w * 128;            // wave-private c-slice [cbase, cbase+128)
    int nseg = (L & 3) * 4;         // n offset 0/4/8/12
    int crow = L >> 2;              // 0..15

    // ---- batch-issue all 8 x loads (long-pole HBM latency, all in flight)
    float4 q[8];
    #pragma unroll
    for (int p = 0; p < 8; ++p) {
        int c = cbase + p * 16 + crow;
        q[p] = *reinterpret_cast<const float4*>(
            x + ((size_t)t * C_ + c) * N_ + n0 + nseg);
    }
    float bk = b[L];

    // ---- prefetch ks=0 A-fragments (wh/wl, L2-hot) while x is in flight
    const unsigned short* wha = wh + (size_t)lid * C_ + cbase + quad * 8;
    const unsigned short* wla = wl + (size_t)lid * C_ + cbase + quad * 8;
    bf16x8 cah[4], cal[4];
    #pragma unroll
    for (int mt = 0; mt < 4; ++mt) {
        cah[mt] = *reinterpret_cast<const bf16x8*>(wha + mt * 16 * C_);
        cal[mt] = *reinterpret_cast<const bf16x8*>(wla + mt * 16 * C_);
    }

    // ---- stage own slice (transpose + hi/lo split), accumulate sumsq
    float ss0 = 0.f, ss1 = 0.f, ss2 = 0.f, ss3 = 0.f;
    #pragma unroll
    for (int p = 0; p < 8; ++p) {
        int c = cbase + p * 16 + crow;
        float vv[4] = {q[p].x, q[p].y, q[p].z, q[p].w};
        ss0 = fmaf(vv[0], vv[0], ss0); ss1 = fmaf(vv[1], vv[1], ss1);
        ss2 = fmaf(vv[2], vv[2], ss2); ss3 = fmaf(vv[3], vv[3], ss3);
        #pragma unroll
        for (int j = 0; j < 4; ++j) {
            unsigned short h = f2bf(vv[j]);
            xh[(nseg + j) * XPITCH + c] = h;
            xl[(nseg + j) * XPITCH + c] = f2bf(vv[j] - bf2f(h));
        }
    }
    // reduce sumsq over same-nseg lanes (stride-4 within wave)
    #pragma unroll
    for (int m = 4; m <= 32; m <<= 1) {
        ss0 += __shfl_xor(ss0, m, 64); ss1 += __shfl_xor(ss1, m, 64);
        ss2 += __shfl_xor(ss2, m, 64); ss3 += __shfl_xor(ss3, m, 64);
    }
    if (L < 4) {
        ssq[w][L * 4 + 0] = ss0; ssq[w][L * 4 + 1] = ss1;
        ssq[w][L * 4 + 2] = ss2; ssq[w][L * 4 + 3] = ss3;
    }

    // ---- MFMA over the wave-private slice: no inter-wave barrier needed.
    // A-fragments double-buffered in registers (prefetch ks+1 during ks).
    f32x4 acc[4];
    #pragma unroll
    for (int mt = 0; mt < 4; ++mt)
        #pragma unroll
        for (int r = 0; r < 4; ++r) acc[mt][r] = 0.f;

    #pragma unroll
    for (int ks = 0; ks < 4; ++ks) {
        bf16x8 nah[4], nal[4];
        #pragma unroll
        for (int mt = 0; mt < 4; ++mt) { nah[mt] = cah[mt]; nal[mt] = cal[mt]; }
        if (ks < 3) {
            #pragma unroll
            for (int mt = 0; mt < 4; ++mt) {
                nah[mt] = *reinterpret_cast<const bf16x8*>(
                    wha + mt * 16 * C_ + (ks + 1) * 32);
                nal[mt] = *reinterpret_cast<const bf16x8*>(
                    wla + mt * 16 * C_ + (ks + 1) * 32);
            }
        }
        int cs = cbase + ks * 32;
        bf16x8 bh = *reinterpret_cast<const bf16x8*>(&xh[lid * XPITCH + cs + quad * 8]);
        bf16x8 bl = *reinterpret_cast<const bf16x8*>(&xl[lid * XPITCH + cs + quad * 8]);
        #pragma unroll
        for (int mt = 0; mt < 4; ++mt) {
            acc[mt] = __builtin_amdgcn_mfma_f32_16x16x32_bf16(cah[mt], bh, acc[mt], 0, 0, 0);
            acc[mt] = __builtin_amdgcn_mfma_f32_16x16x32_bf16(cal[mt], bh, acc[mt], 0, 0, 0);
            acc[mt] = __builtin_amdgcn_mfma_f32_16x16x32_bf16(cah[mt], bl, acc[mt], 0, 0, 0);
        }
        #pragma unroll
        for (int mt = 0; mt < 4; ++mt) { cah[mt] = nah[mt]; cal[mt] = nal[mt]; }
    }
    __syncthreads();   // all waves done reading stage -> reuse as red
    {
        float* rp = red + w * (16 * 68);
        #pragma unroll
        for (int mt = 0; mt < 4; ++mt)
            *reinterpret_cast<f32x4*>(&rp[lid * 68 + mt * 16 + quad * 4]) = acc[mt];
    }
    __syncthreads();

    // ---- softmax: wave w handles n rows w*4..w*4+3; lane L = k.
    // 4 rows processed in lockstep so the shfl chains overlap.
    float vv[4], iv[4];
    #pragma unroll
    for (int i = 0; i < 4; ++i) {
        int n = w * 4 + i;
        float s = ssq[0][n] + ssq[1][n] + ssq[2][n] + ssq[3][n];
        iv[i] = 1.0f / fmaxf(sqrtf(s), EPSV);
        float v = red[0 * 1088 + n * 68 + L] + red[1 * 1088 + n * 68 + L]
                + red[2 * 1088 + n * 68 + L] + red[3 * 1088 + n * 68 + L];
        vv[i] = fmaf(v, iv[i], bk);
    }
    float mx[4] = {vv[0], vv[1], vv[2], vv[3]};
    #pragma unroll
    for (int m = 1; m <= 32; m <<= 1) {
        #pragma unroll
        for (int i = 0; i < 4; ++i) mx[i] = fmaxf(mx[i], __shfl_xor(mx[i], m, 64));
    }
    float e[4], se[4];
    #pragma unroll
    for (int i = 0; i < 4; ++i) { e[i] = __expf(vv[i] - mx[i]); se[i] = e[i]; }
    #pragma unroll
    for (int m = 1; m <= 32; m <<= 1) {
        #pragma unroll
        for (int i = 0; i < 4; ++i) se[i] += __shfl_xor(se[i], m, 64);
    }
    float asl = 0.f;
    unsigned short av[4];
    #pragma unroll
    for (int i = 0; i < 4; ++i) {
        float a = e[i] / se[i];
        av[i] = f2bf(a * iv[i]);
        asl += a;
    }
    atomicAdd(&asum[t * 64 + L], asl);
    ushort4 st; st.x = av[0]; st.y = av[1]; st.z = av[2]; st.w = av[3];
    *reinterpret_cast<ushort4*>(aT + ((size_t)t * 64 + L) * NA_ + n0 + w * 4) = st;
    // fused tail-zero (n=784..800) replaces the 3 MB aT memset
    if (blockIdx.x == 48) {
        ushort4 z; z.x = 0; z.y = 0; z.z = 0; z.w = 0;
        *reinterpret_cast<ushort4*>(aT + ((size_t)t * 64 + L) * NA_ + 784 + w * 4) = z;
    }
}

// vlad[t][k][c] = sum_n ahat[k][n]*x[c][n] - asum[k]*cent[k][c]; also g2[t][k]=sum_c v^2.
// grid (32, 30), 256 thr. Block: 16 c x 64 k; n-reduction split over 4 waves.
// v2: software-pipelined (prefetch next s-step's x + aT fragments).
__global__ __launch_bounds__(256) void k_vlad(
    const float* __restrict__ x, const unsigned short* __restrict__ aT,
    const float* __restrict__ asum, const float* __restrict__ cent,
    float* __restrict__ vlad, float* __restrict__ g2)
{
    __shared__ float red[4][16 * 68];
    int t = blockIdx.y, c0 = blockIdx.x * 16;
    int tid = threadIdx.x;
    int w = tid >> 6, L = tid & 63, lid = L & 15, quad = L >> 4;

    f32x4 acc[4];
    #pragma unroll
    for (int mt = 0; mt < 4; ++mt)
        #pragma unroll
        for (int r = 0; r < 4; ++r) acc[mt][r] = 0.f;

    const float* xrow = x + ((size_t)t * C_ + c0 + lid) * N_;
    const unsigned short* a0 = aT + (size_t)t * 64 * NA_ + (size_t)lid * NA_;

    // epilogue operands issued early (latency hidden under the main loop)
    int k = tid >> 2, cs4 = (tid & 3) * 4;
    float as = asum[t * 64 + k];
    float4 cv = *reinterpret_cast<const float4*>(cent + k * C_ + c0 + cs4);

    // prologue: load step s=w
    int nb = w * 32 + quad * 8;
    int nc = nb > 776 ? 776 : nb;   // clamped lanes hit aT zeros
    float4 x0c = *reinterpret_cast<const float4*>(xrow + nc);
    float4 x1c = *reinterpret_cast<const float4*>(xrow + nc + 4);
    bf16x8 f0 = *reinterpret_cast<const bf16x8*>(a0 + nb);
    bf16x8 f1 = *reinterpret_cast<const bf16x8*>(a0 + 16 * NA_ + nb);
    bf16x8 f2 = *reinterpret_cast<const bf16x8*>(a0 + 32 * NA_ + nb);
    bf16x8 f3 = *reinterpret_cast<const bf16x8*>(a0 + 48 * NA_ + nb);

    for (int s = w; s < 25; s += 4) {
        int sn = s + 4;
        float4 x0n = x0c, x1n = x1c;
        bf16x8 g0 = f0, g1 = f1, g2v = f2, g3 = f3;
        if (sn < 25) {  // wave-uniform branch: prefetch next step
            int nb2 = sn * 32 + quad * 8;
            int nc2 = nb2 > 776 ? 776 : nb2;
            x0n = *reinterpret_cast<const float4*>(xrow + nc2);
            x1n = *reinterpret_cast<const float4*>(xrow + nc2 + 4);
            g0 = *reinterpret_cast<const bf16x8*>(a0 + nb2);
            g1 = *reinterpret_cast<const bf16x8*>(a0 + 16 * NA_ + nb2);
            g2v = *reinterpret_cast<const bf16x8*>(a0 + 32 * NA_ + nb2);
            g3 = *reinterpret_cast<const bf16x8*>(a0 + 48 * NA_ + nb2);
        }
        bf16x8 bb;
        bb[0] = (short)f2bf(x0c.x); bb[1] = (short)f2bf(x0c.y);
        bb[2] = (short)f2bf(x0c.z); bb[3] = (short)f2bf(x0c.w);
        bb[4] = (short)f2bf(x1c.x); bb[5] = (short)f2bf(x1c.y);
        bb[6] = (short)f2bf(x1c.z); bb[7] = (short)f2bf(x1c.w);
        acc[0] = __builtin_amdgcn_mfma_f32_16x16x32_bf16(f0, bb, acc[0], 0, 0, 0);
        acc[1] = __builtin_amdgcn_mfma_f32_16x16x32_bf16(f1, bb, acc[1], 0, 0, 0);
        acc[2] = __builtin_amdgcn_mfma_f32_16x16x32_bf16(f2, bb, acc[2], 0, 0, 0);
        acc[3] = __builtin_amdgcn_mfma_f32_16x16x32_bf16(f3, bb, acc[3], 0, 0, 0);
        x0c = x0n; x1c = x1n; f0 = g0; f1 = g1; f2 = g2v; f3 = g3;
    }
    {
        float* rp = &red[w][0];
        #pragma unroll
        for (int mt = 0; mt < 4; ++mt)
            *reinterpret_cast<f32x4*>(&rp[lid * 68 + mt * 16 + quad * 4]) = acc[mt];
    }
    __syncthreads();

    // epilogue: thread -> k = tid>>2, 4 c
    float4 vout;
    float s2 = 0.f;
    #pragma unroll
    for (int j = 0; j < 4; ++j) {
        int cc = cs4 + j;
        float v = red[0][cc * 68 + k] + red[1][cc * 68 + k]
                + red[2][cc * 68 + k] + red[3][cc * 68 + k];
        v -= as * ((const float*)&cv)[j];
        ((float*)&vout)[j] = v;
        s2 = fmaf(v, v, s2);
    }
    *reinterpret_cast<float4*>(vlad + ((size_t)t * 64 + k) * C_ + c0 + cs4) = vout;
    s2 += __shfl_xor(s2, 1, 64);
    s2 += __shfl_xor(s2, 2, 64);
    if ((tid & 3) == 0) atomicAdd(&g2[t * 64 + k], s2);
}

// out[k*512+c] = sum_t vlad * inv_intra * inv_g  (norm factors from g2)
__global__ __launch_bounds__(256) void k_out(
    const float* __restrict__ vlad, const float* __restrict__ g2,
    float* __restrict__ out)
{
    __shared__ float intr[1920];
    __shared__ float gl[1920];
    __shared__ float sinv[T_];
    int tid = threadIdx.x;
    for (int i = tid; i < 1920; i += 256) {
        float s = g2[i];
        gl[i] = s;
        intr[i] = 1.0f / fmaxf(sqrtf(s), EPSV);
    }
    __syncthreads();
    if (tid < T_) {
        float s = 0.f;
        #pragma unroll 8
        for (int k = 0; k < 64; ++k) {
            float iv = intr[tid * 64 + k];
            s += gl[tid * 64 + k] * iv * iv;
        }
        sinv[tid] = 1.0f / fmaxf(sqrtf(s), EPSV);
    }
    __syncthreads();
    int idx = blockIdx.x * 256 + tid;  // k*512+c
    int k = idx >> 9;
    float s = 0.f;
    #pragma unroll 5
    for (int t = 0; t < T_; ++t)
        s += vlad[(size_t)t * 32768 + idx] * intr[t * 64 + k] * sinv[t];
    out[idx] = s;
}

extern "C" void kernel_launch(void* const* d_in, const int* in_sizes, int n_in,
                              void* d_out, int out_size, void* d_ws, size_t ws_size,
                              hipStream_t stream) {
    const float* x    = (const float*)d_in[0];   // 30*512*784
    const float* cent = (const float*)d_in[1];   // 64*512
    const float* w    = (const float*)d_in[2];   // 64*512
    const float* b    = (const float*)d_in[3];   // 64
    float* out = (float*)d_out;

    char* p = (char*)d_ws;
    unsigned short* wh = (unsigned short*)p;  p += 65536;
    unsigned short* wl = (unsigned short*)p;  p += 65536;
    float* asum = (float*)p;                  p += 1920 * 4;
    float* g2   = (float*)p;                  p += 1920 * 4;
    unsigned short* aT = (unsigned short*)p;  p += (size_t)T_ * 64 * NA_ * 2;  // 3,072,000
    float* vlad = (float*)p;                  p += (size_t)T_ * 64 * C_ * 4;   // 3,932,160
    // total ~= 7.2 MB

    k_prep<<<128, 256, 0, stream>>>(w, wh, wl);
    hipMemsetAsync(asum, 0, 2 * 1920 * 4, stream);            // asum + g2 (contiguous)
    // aT tail-zero now fused into k_assign (blockIdx.x == 48)
    k_assign<<<dim3(49, T_), 256, 0, stream>>>(x, wh, wl, b, aT, asum);
    k_vlad<<<dim3(32, T_), 256, 0, stream>>>(x, aT, asum, cent, vlad, g2);
    k_out<<<128, 256, 0, stream>>>(vlad, g2, out);
}